// Round 6
// baseline (123.792 us; speedup 1.0000x reference)
//
#include <hip/hip_runtime.h>

// TransformerBlockQuantum: [128, 8192, 8] fp32 in/out.
// R6 = R5 + (a) launch_bounds(256,8) for 32 waves/CU, (b) Wq & q-bias
// pre-scaled by 1/2pi with theta_attn folded in (cos takes revolutions
// directly), (c) z@Wc via dot2 with packed Wc row-pairs.

#define NTOK   (128 * 8192)              // 1048576 tokens
#define T      2
#define NTHREADS 256
#define NBLOCKS  (NTOK / (T * NTHREADS)) // 2048
#define TSTRIDE  (NTOK / T)              // 524288
#define LN_EPS 1e-5f
#define INV2PI 0.15915494309189535f

typedef __fp16 half2_t __attribute__((ext_vector_type(2)));

union PK { unsigned u; half2_t h; };

__device__ __forceinline__ float fast_cos_rev(float xrev) {
    return __builtin_amdgcn_cosf(xrev);        // v_cos_f32: revolutions in
}
__device__ __forceinline__ float fast_cos(float x) {
    return __builtin_amdgcn_cosf(x * INV2PI);
}
__device__ __forceinline__ float fast_rsqrt(float x) {
    return __builtin_amdgcn_rsqf(x);
}
__device__ __forceinline__ unsigned packh2(float a, float b) {
    PK c; c.h = __builtin_amdgcn_cvt_pkrtz(a, b); return c.u;
}
__device__ __forceinline__ float dot2(half2_t a, unsigned bw, float c) {
    PK b; b.u = bw;
    return __builtin_amdgcn_fdot2(a, b.h, c, false);
}

// ---- prep: pack weights into half2 pairs (along the K dim of each matvec) ----
// ws layout (uint32):
//   [0,32)    WqP[k][p]  = (Wq[2p][k], Wq[2p+1][k]) * INV2PI
//   [32,160)  W1P[m][p]  = (W1[2p][32+m... wait]..)  W1P[m][p]=(W1[2p][m],W1[2p+1][m])
//   [160,288) W2P[mp][j] = (W2[2mp][j], W2[2mp+1][j])
//   [288,320) WcP[kp][j] = (Wc[2kp][j], Wc[2kp+1][j])
//   [320,328) qbias[k]   = (bq[k]+tha[k]) * INV2PI   (float bits)
__global__ void pack_weights(const float* __restrict__ Wq,
                             const float* __restrict__ W1,
                             const float* __restrict__ W2,
                             const float* __restrict__ Wc,
                             const float* __restrict__ bq,
                             const float* __restrict__ tha,
                             unsigned* __restrict__ ws)
{
    int idx = threadIdx.x;
    if (idx < 32) {
        int k = idx >> 2, p = idx & 3;
        ws[idx] = packh2(Wq[(2 * p) * 8 + k] * INV2PI, Wq[(2 * p + 1) * 8 + k] * INV2PI);
    } else if (idx < 160) {
        int i2 = idx - 32;
        int m = i2 >> 2, p = i2 & 3;
        ws[idx] = packh2(W1[(2 * p) * 32 + m], W1[(2 * p + 1) * 32 + m]);
    } else if (idx < 288) {
        int i2 = idx - 160;
        int mp = i2 >> 3, j = i2 & 7;
        ws[idx] = packh2(W2[(2 * mp) * 8 + j], W2[(2 * mp + 1) * 8 + j]);
    } else if (idx < 320) {
        int i2 = idx - 288;
        int kp = i2 >> 3, j = i2 & 7;
        ws[idx] = packh2(Wc[(2 * kp) * 8 + j], Wc[(2 * kp + 1) * 8 + j]);
    } else if (idx < 328) {
        int k = idx - 320;
        ws[idx] = __float_as_uint((bq[k] + tha[k]) * INV2PI);
    }
}

__global__ __launch_bounds__(NTHREADS, 8)
void qtb_kernel(const float* __restrict__ x,
                const float* __restrict__ bc,
                const float* __restrict__ g1,  const float* __restrict__ be1,
                const float* __restrict__ thf,
                const float* __restrict__ b1,
                const float* __restrict__ b2,
                const float* __restrict__ g2,  const float* __restrict__ be2,
                const unsigned* __restrict__ wp,   // packed weights in ws
                float* __restrict__ out)
{
    const int g = blockIdx.x * NTHREADS + threadIdx.x;  // 0 .. TSTRIDE-1
    const float* qb = reinterpret_cast<const float*>(wp + 320);

    // ---- load x: T tokens * 8 feats, coalesced float4 pairs; pack i-pairs ----
    float xv[T][8];
    half2_t xp[T][4];
#pragma unroll
    for (int t = 0; t < T; ++t) {
        const float4* p = reinterpret_cast<const float4*>(x) + (size_t)(t * TSTRIDE + g) * 2;
        float4 a = p[0];
        float4 b = p[1];
        xv[t][0] = a.x; xv[t][1] = a.y; xv[t][2] = a.z; xv[t][3] = a.w;
        xv[t][4] = b.x; xv[t][5] = b.y; xv[t][6] = b.z; xv[t][7] = b.w;
        xp[t][0] = __builtin_amdgcn_cvt_pkrtz(a.x, a.y);
        xp[t][1] = __builtin_amdgcn_cvt_pkrtz(a.z, a.w);
        xp[t][2] = __builtin_amdgcn_cvt_pkrtz(b.x, b.y);
        xp[t][3] = __builtin_amdgcn_cvt_pkrtz(b.z, b.w);
    }

    // ---- attention: per k: q (revolutions) via dot2, cos; then cumprods ----
    float ca[T][8];
#pragma unroll
    for (int k = 0; k < 8; ++k) {
        const float bqk = qb[k];
#pragma unroll
        for (int t = 0; t < T; ++t) {
            float q = bqk;
#pragma unroll
            for (int p = 0; p < 4; ++p) q = dot2(xp[t][p], wp[k * 4 + p], q);
            ca[t][k] = fast_cos_rev(q);
        }
    }

    // ---- z via cumprods, attn = z@Wc + bc (dot2 over k-pairs) ----
    float attn[T][8];
#pragma unroll
    for (int t = 0; t < T; ++t)
#pragma unroll
        for (int j = 0; j < 8; ++j) attn[t][j] = bc[j];
#pragma unroll
    for (int t = 0; t < T; ++t) {
        float z[8];
        float cp  = ca[t][0];
        float cp1 = 1.0f;
#pragma unroll
        for (int k = 1; k < 8; ++k) {
            cp  *= ca[t][k];
            cp1 *= ca[t][k];
            z[k] = cp;
        }
        z[0] = cp1;
        half2_t zp[4];
#pragma unroll
        for (int p = 0; p < 4; ++p)
            zp[p] = __builtin_amdgcn_cvt_pkrtz(z[2 * p], z[2 * p + 1]);
#pragma unroll
        for (int p = 0; p < 4; ++p)
#pragma unroll
            for (int j = 0; j < 8; ++j)
                attn[t][j] = dot2(zp[p], wp[288 + p * 8 + j], attn[t][j]);
    }

    // ---- LN1 + zf = cos(thf) * cos(x1), packed i-pairs for FFN ----
    float cf[8];
#pragma unroll
    for (int j = 0; j < 8; ++j) cf[j] = fast_cos(thf[j]);
    float sg1[8], sb1[8];
#pragma unroll
    for (int j = 0; j < 8; ++j) { sg1[j] = g1[j]; sb1[j] = be1[j]; }

    half2_t zfp[T][4];
#pragma unroll
    for (int t = 0; t < T; ++t) {
        float y[8];
        float s = 0.f;
#pragma unroll
        for (int j = 0; j < 8; ++j) { y[j] = xv[t][j] + attn[t][j]; s += y[j]; }
        float m = s * 0.125f;
        float v = 0.f;
#pragma unroll
        for (int j = 0; j < 8; ++j) { float d = y[j] - m; v += d * d; }
        float r = fast_rsqrt(v * 0.125f + LN_EPS);
        float zf[8];
#pragma unroll
        for (int j = 0; j < 8; ++j) {
            float x1 = (y[j] - m) * r * sg1[j] + sb1[j];
            xv[t][j] = x1;                       // keep x1 for residual 2
            zf[j] = cf[j] * fast_cos(x1);
        }
#pragma unroll
        for (int p = 0; p < 4; ++p)
            zfp[t][p] = __builtin_amdgcn_cvt_pkrtz(zf[2 * p], zf[2 * p + 1]);
    }

    // ---- FFN via dot2: h-pairs (m,m+1), outer product as dot2 over m-pairs ----
    float ffn[T][8];
    {
        float sb2[8];
#pragma unroll
        for (int j = 0; j < 8; ++j) sb2[j] = b2[j];
#pragma unroll
        for (int t = 0; t < T; ++t)
#pragma unroll
            for (int j = 0; j < 8; ++j) ffn[t][j] = sb2[j];
    }
#pragma unroll
    for (int mp = 0; mp < 16; ++mp) {
        const int m0 = 2 * mp, m1 = 2 * mp + 1;
        const float b1a = b1[m0];
        const float b1b = b1[m1];
        unsigned w2p[8];
#pragma unroll
        for (int j = 0; j < 8; ++j) w2p[j] = wp[160 + mp * 8 + j];
#pragma unroll
        for (int t = 0; t < T; ++t) {
            float h0 = b1a, h1 = b1b;
#pragma unroll
            for (int p = 0; p < 4; ++p) {
                h0 = dot2(zfp[t][p], wp[32 + m0 * 4 + p], h0);
                h1 = dot2(zfp[t][p], wp[32 + m1 * 4 + p], h1);
            }
            h0 = fmaxf(h0, 0.f);
            h1 = fmaxf(h1, 0.f);
            half2_t hp = __builtin_amdgcn_cvt_pkrtz(h0, h1);
#pragma unroll
            for (int j = 0; j < 8; ++j) ffn[t][j] = dot2(hp, w2p[j], ffn[t][j]);
        }
    }

    // ---- LN2 + store ----
    float sg2[8], sbb2[8];
#pragma unroll
    for (int j = 0; j < 8; ++j) { sg2[j] = g2[j]; sbb2[j] = be2[j]; }
#pragma unroll
    for (int t = 0; t < T; ++t) {
        float y[8];
        float s = 0.f;
#pragma unroll
        for (int j = 0; j < 8; ++j) { y[j] = xv[t][j] + ffn[t][j]; s += y[j]; }
        float m = s * 0.125f;
        float v = 0.f;
#pragma unroll
        for (int j = 0; j < 8; ++j) { float d = y[j] - m; v += d * d; }
        float r = fast_rsqrt(v * 0.125f + LN_EPS);
        float o[8];
#pragma unroll
        for (int j = 0; j < 8; ++j) o[j] = (y[j] - m) * r * sg2[j] + sbb2[j];
        float4* q = reinterpret_cast<float4*>(out) + (size_t)(t * TSTRIDE + g) * 2;
        q[0] = make_float4(o[0], o[1], o[2], o[3]);
        q[1] = make_float4(o[4], o[5], o[6], o[7]);
    }
}

extern "C" void kernel_launch(void* const* d_in, const int* in_sizes, int n_in,
                              void* d_out, int out_size, void* d_ws, size_t ws_size,
                              hipStream_t stream) {
    (void)in_sizes; (void)n_in; (void)ws_size; (void)out_size;
    unsigned* wp = (unsigned*)d_ws;
    pack_weights<<<1, 384, 0, stream>>>(
        (const float*)d_in[1],   // Wq
        (const float*)d_in[9],   // W1
        (const float*)d_in[11],  // W2
        (const float*)d_in[4],   // Wc
        (const float*)d_in[2],   // bq
        (const float*)d_in[3],   // theta_attn
        wp);
    qtb_kernel<<<NBLOCKS, NTHREADS, 0, stream>>>(
        (const float*)d_in[0],  // x
        (const float*)d_in[5],  // bc
        (const float*)d_in[6],  // g1
        (const float*)d_in[7],  // beta1
        (const float*)d_in[8],  // theta_ffn
        (const float*)d_in[10], // b1
        (const float*)d_in[12], // b2
        (const float*)d_in[13], // g2
        (const float*)d_in[14], // beta2
        wp,
        (float*)d_out);
}

// Round 7
// 114.854 us; speedup vs baseline: 1.0778x; 1.0778x over previous
//
#include <hip/hip_runtime.h>

// TransformerBlockQuantum: [128, 8192, 8] fp32 in/out.
// R7: T=1 (lane=token). Attention kept on VALU (dot2, R6 structure).
// FFN offloaded to MFMA f16 (2 GEMMs: [64x8]@[8x32] relu [64x32]@[32x8])
// with wave-local LDS transposes (no barriers; lgkmcnt ordering only).
// Pack kernel emits dot2-packed Wq/Wc + per-lane MFMA B-fragments for W1/W2.

#define NTOK   (128 * 8192)              // 1048576 tokens
#define NTHREADS 256
#define NBLOCKS  (NTOK / NTHREADS)       // 4096
#define LN_EPS 1e-5f
#define INV2PI 0.15915494309189535f

typedef __fp16 half2_t __attribute__((ext_vector_type(2)));
typedef __fp16 half8_t __attribute__((ext_vector_type(8)));
typedef float  float4_t __attribute__((ext_vector_type(4)));

union PK  { unsigned u; half2_t h; };
union U4H { uint4 u; half8_t h; half2_t h2[4]; };

__device__ __forceinline__ float fast_cos_rev(float xrev) {
    return __builtin_amdgcn_cosf(xrev);        // v_cos_f32: revolutions in
}
__device__ __forceinline__ float fast_cos(float x) {
    return __builtin_amdgcn_cosf(x * INV2PI);
}
__device__ __forceinline__ float fast_rsqrt(float x) {
    return __builtin_amdgcn_rsqf(x);
}
__device__ __forceinline__ unsigned packh2(float a, float b) {
    PK c; c.h = __builtin_amdgcn_cvt_pkrtz(a, b); return c.u;
}
__device__ __forceinline__ float dot2(half2_t a, unsigned bw, float c) {
    PK b; b.u = bw;
    return __builtin_amdgcn_fdot2(a, b.h, c, false);
}

// ---- prep kernel ----------------------------------------------------------
// ws layout (uint32 words):
//   [0,32)    WqP[k][p]  = (Wq[2p][k], Wq[2p+1][k]) * INV2PI   (dot2 pairs)
//   [32,64)   WcP[kp][j] = (Wc[2kp][j], Wc[2kp+1][j])          (dot2 pairs)
//   [64,72)   qbias[k]   = (bq[k]+tha[k]) * INV2PI   (float bits)
//   [128,384) B1a frag:  uint4 per lane L: W1[j][n0] f16 pairs, q==0 else 0
//   [384,640) B1b frag:  same with n0+16
//   [640,896) B2  frag:  W2[8q+j][n0] f16 pairs, n0<8 else 0
// Frag layout: A/B[m|n = lane&15][k = (lane>>4)*8 + j], pairs (2p,2p+1) along k.
__global__ void pack_weights(const float* __restrict__ Wq,
                             const float* __restrict__ W1,
                             const float* __restrict__ W2,
                             const float* __restrict__ Wc,
                             const float* __restrict__ bq,
                             const float* __restrict__ tha,
                             unsigned* __restrict__ ws)
{
    int idx = threadIdx.x;
    if (idx < 32) {
        int k = idx >> 2, p = idx & 3;
        ws[idx] = packh2(Wq[(2 * p) * 8 + k] * INV2PI, Wq[(2 * p + 1) * 8 + k] * INV2PI);
    } else if (idx < 64) {
        int i2 = idx - 32;
        int kp = i2 >> 3, j = i2 & 7;
        ws[idx] = packh2(Wc[(2 * kp) * 8 + j], Wc[(2 * kp + 1) * 8 + j]);
    } else if (idx < 72) {
        int k = idx - 64;
        ws[idx] = __float_as_uint((bq[k] + tha[k]) * INV2PI);
    } else if (idx >= 128 && idx < 320) {
        int t  = (idx - 128) & 63;          // lane id
        int tb = (idx - 128) >> 6;          // 0=B1a, 1=B1b, 2=B2
        int n0 = t & 15, q = t >> 4;
        uint4 w = make_uint4(0u, 0u, 0u, 0u);
        unsigned r[4] = {0u, 0u, 0u, 0u};
        if (tb == 0) {           // W1 [8][32], rows k<8 real (q==0)
            if (q == 0)
                for (int p = 0; p < 4; ++p)
                    r[p] = packh2(W1[(2 * p) * 32 + n0], W1[(2 * p + 1) * 32 + n0]);
        } else if (tb == 1) {
            if (q == 0)
                for (int p = 0; p < 4; ++p)
                    r[p] = packh2(W1[(2 * p) * 32 + n0 + 16], W1[(2 * p + 1) * 32 + n0 + 16]);
        } else {                 // W2 [32][8], cols n0<8 real, k = 8q+j
            if (n0 < 8)
                for (int p = 0; p < 4; ++p)
                    r[p] = packh2(W2[(8 * q + 2 * p) * 8 + n0], W2[(8 * q + 2 * p + 1) * 8 + n0]);
        }
        w.x = r[0]; w.y = r[1]; w.z = r[2]; w.w = r[3];
        reinterpret_cast<uint4*>(ws)[32 + tb * 64 + t] = w;
    }
}

// ---- main kernel ----------------------------------------------------------
__global__ __launch_bounds__(NTHREADS, 4)
void qtb_kernel(const float* __restrict__ x,
                const float* __restrict__ bc,
                const float* __restrict__ g1,  const float* __restrict__ be1,
                const float* __restrict__ thf,
                const float* __restrict__ b1,
                const float* __restrict__ b2,
                const float* __restrict__ g2,  const float* __restrict__ be2,
                const unsigned* __restrict__ wp,
                float* __restrict__ out)
{
    const int tid  = threadIdx.x;
    const int wave = tid >> 6;
    const int lane = tid & 63;
    const int col  = lane & 15;
    const int quad = lane >> 4;
    const int g    = blockIdx.x * NTHREADS + tid;   // token id
    const float* qb = reinterpret_cast<const float*>(wp + 64);

    // wave-private LDS slices (no __syncthreads needed; same-wave lgkmcnt ordering)
    __shared__ uint4 zbuf[4][64];        // zf f16x8 per token
    __shared__ float hbuf[4][16 * 34];   // h transpose buffer (pad 34)
    __shared__ float fbuf[4][64 * 9];    // ffn transpose buffer (pad 9)

    // ---- MFMA weight fragments + bias C-inits ----
    const uint4* fr = reinterpret_cast<const uint4*>(wp);
    U4H B1a, B1b, B2;
    B1a.u = fr[32 + lane];
    B1b.u = fr[96 + lane];
    B2.u  = fr[160 + lane];
    const float b1a_s = b1[col];
    const float b1b_s = b1[col + 16];
    const float b2_s  = (col < 8) ? b2[col & 7] : 0.f;

    // ---- load x: 8 feats, coalesced float4 pair ----
    float xv[8];
    half2_t xp[4];
    {
        const float4* p = reinterpret_cast<const float4*>(x) + (size_t)g * 2;
        float4 a = p[0];
        float4 b = p[1];
        xv[0] = a.x; xv[1] = a.y; xv[2] = a.z; xv[3] = a.w;
        xv[4] = b.x; xv[5] = b.y; xv[6] = b.z; xv[7] = b.w;
        xp[0] = __builtin_amdgcn_cvt_pkrtz(a.x, a.y);
        xp[1] = __builtin_amdgcn_cvt_pkrtz(a.z, a.w);
        xp[2] = __builtin_amdgcn_cvt_pkrtz(b.x, b.y);
        xp[3] = __builtin_amdgcn_cvt_pkrtz(b.z, b.w);
    }

    // ---- attention: q (revolutions) via dot2, cos, cumprods, z@Wc via dot2 ----
    float ca[8];
#pragma unroll
    for (int k = 0; k < 8; ++k) {
        float q = qb[k];
#pragma unroll
        for (int p = 0; p < 4; ++p) q = dot2(xp[p], wp[k * 4 + p], q);
        ca[k] = fast_cos_rev(q);
    }
    float attn[8];
#pragma unroll
    for (int j = 0; j < 8; ++j) attn[j] = bc[j];
    {
        float z[8];
        float cp  = ca[0];
        float cp1 = 1.0f;
#pragma unroll
        for (int k = 1; k < 8; ++k) {
            cp  *= ca[k];
            cp1 *= ca[k];
            z[k] = cp;
        }
        z[0] = cp1;
        half2_t zp[4];
#pragma unroll
        for (int p = 0; p < 4; ++p)
            zp[p] = __builtin_amdgcn_cvt_pkrtz(z[2 * p], z[2 * p + 1]);
#pragma unroll
        for (int p = 0; p < 4; ++p)
#pragma unroll
            for (int j = 0; j < 8; ++j)
                attn[j] = dot2(zp[p], wp[32 + p * 8 + j], attn[j]);
    }

    // ---- LN1 + zf = cos(thf) * cos(x1); keep x1 in xv ----
    {
        float y[8];
        float s = 0.f;
#pragma unroll
        for (int j = 0; j < 8; ++j) { y[j] = xv[j] + attn[j]; s += y[j]; }
        float m = s * 0.125f;
        float v = 0.f;
#pragma unroll
        for (int j = 0; j < 8; ++j) { float d = y[j] - m; v += d * d; }
        float r = fast_rsqrt(v * 0.125f + LN_EPS);
        float zf[8];
#pragma unroll
        for (int j = 0; j < 8; ++j) {
            float x1 = (y[j] - m) * r * g1[j] + be1[j];
            xv[j] = x1;
            zf[j] = fast_cos(thf[j]) * fast_cos(x1);
        }
        U4H zpk;
#pragma unroll
        for (int p = 0; p < 4; ++p)
            zpk.h2[p] = __builtin_amdgcn_cvt_pkrtz(zf[2 * p], zf[2 * p + 1]);
        zbuf[wave][lane] = zpk.u;
    }

    // ---- FFN on MFMA: per 16-token group: GEMM1 (2 mfma) -> relu -> GEMM2 ----
#pragma unroll
    for (int grp = 0; grp < 4; ++grp) {
        // A1: zf of token (grp*16 + col), broadcast across quads (k>=8 of B is 0)
        U4H A1; A1.u = zbuf[wave][grp * 16 + col];
        float4_t c1a = {b1a_s, b1a_s, b1a_s, b1a_s};
        float4_t c1b = {b1b_s, b1b_s, b1b_s, b1b_s};
        float4_t h0 = __builtin_amdgcn_mfma_f32_16x16x32_f16(A1.h, B1a.h, c1a, 0, 0, 0);
        float4_t h1 = __builtin_amdgcn_mfma_f32_16x16x32_f16(A1.h, B1b.h, c1b, 0, 0, 0);
        // relu + transpose via LDS: h[tok=4*quad+r][n], row stride 34
#pragma unroll
        for (int r = 0; r < 4; ++r) {
            hbuf[wave][(4 * quad + r) * 34 + col]      = fmaxf(h0[r], 0.f);
            hbuf[wave][(4 * quad + r) * 34 + col + 16] = fmaxf(h1[r], 0.f);
        }
        // A2: h[m=col][k=8*quad + j]
        U4H A2;
#pragma unroll
        for (int p = 0; p < 4; ++p) {
            float ha = hbuf[wave][col * 34 + 8 * quad + 2 * p];
            float hb = hbuf[wave][col * 34 + 8 * quad + 2 * p + 1];
            A2.h2[p] = __builtin_amdgcn_cvt_pkrtz(ha, hb);
        }
        float4_t c2 = {b2_s, b2_s, b2_s, b2_s};
        float4_t f = __builtin_amdgcn_mfma_f32_16x16x32_f16(A2.h, B2.h, c2, 0, 0, 0);
        // ffn out: D[tok=4*quad+r][j=col], only cols<8 valid; row stride 9
        if (col < 8) {
#pragma unroll
            for (int r = 0; r < 4; ++r)
                fbuf[wave][(grp * 16 + 4 * quad + r) * 9 + col] = f[r];
        }
    }

    // ---- LN2 + store ----
    {
        float y[8];
        float s = 0.f;
#pragma unroll
        for (int j = 0; j < 8; ++j) {
            y[j] = xv[j] + fbuf[wave][lane * 9 + j];
            s += y[j];
        }
        float m = s * 0.125f;
        float v = 0.f;
#pragma unroll
        for (int j = 0; j < 8; ++j) { float d = y[j] - m; v += d * d; }
        float r = fast_rsqrt(v * 0.125f + LN_EPS);
        float o[8];
#pragma unroll
        for (int j = 0; j < 8; ++j) o[j] = (y[j] - m) * r * g2[j] + be2[j];
        float4* q = reinterpret_cast<float4*>(out) + (size_t)g * 2;
        q[0] = make_float4(o[0], o[1], o[2], o[3]);
        q[1] = make_float4(o[4], o[5], o[6], o[7]);
    }
}

extern "C" void kernel_launch(void* const* d_in, const int* in_sizes, int n_in,
                              void* d_out, int out_size, void* d_ws, size_t ws_size,
                              hipStream_t stream) {
    (void)in_sizes; (void)n_in; (void)ws_size; (void)out_size;
    unsigned* wp = (unsigned*)d_ws;
    pack_weights<<<1, 320, 0, stream>>>(
        (const float*)d_in[1],   // Wq
        (const float*)d_in[9],   // W1
        (const float*)d_in[11],  // W2
        (const float*)d_in[4],   // Wc
        (const float*)d_in[2],   // bq
        (const float*)d_in[3],   // theta_attn
        wp);
    qtb_kernel<<<NBLOCKS, NTHREADS, 0, stream>>>(
        (const float*)d_in[0],  // x
        (const float*)d_in[5],  // bc
        (const float*)d_in[6],  // g1
        (const float*)d_in[7],  // beta1
        (const float*)d_in[8],  // theta_ffn
        (const float*)d_in[10], // b1
        (const float*)d_in[12], // b2
        (const float*)d_in[13], // g2
        (const float*)d_in[14], // beta2
        wp,
        (float*)d_out);
}

// Round 8
// 113.404 us; speedup vs baseline: 1.0916x; 1.0128x over previous
//
#include <hip/hip_runtime.h>

// TransformerBlockQuantum: [128, 8192, 8] fp32 in/out.
// R8 = R7 + (a) launch_bounds(256,8) -> 32 waves/CU (was 16; latency-bound),
// (b) hbuf packed f16 (j,j+16) stride-20 -> 2x ds_read_b128 + v_perm for A2,
// LDS 22->18 KB/block so 8 blocks/CU fit, (c) x load hoisted, cos(theta_ffn)
// precomputed in pack kernel.

#define NTOK   (128 * 8192)              // 1048576 tokens
#define NTHREADS 256
#define NBLOCKS  (NTOK / NTHREADS)       // 4096
#define LN_EPS 1e-5f
#define INV2PI 0.15915494309189535f

typedef __fp16 half2_t __attribute__((ext_vector_type(2)));
typedef __fp16 half8_t __attribute__((ext_vector_type(8)));
typedef float  float4_t __attribute__((ext_vector_type(4)));

union PK  { unsigned u; half2_t h; };
union U4H { uint4 u; half8_t h; half2_t h2[4]; };

__device__ __forceinline__ float fast_cos_rev(float xrev) {
    return __builtin_amdgcn_cosf(xrev);        // v_cos_f32: revolutions in
}
__device__ __forceinline__ float fast_cos(float x) {
    return __builtin_amdgcn_cosf(x * INV2PI);
}
__device__ __forceinline__ float fast_rsqrt(float x) {
    return __builtin_amdgcn_rsqf(x);
}
__device__ __forceinline__ unsigned packh2(float a, float b) {
    PK c; c.h = __builtin_amdgcn_cvt_pkrtz(a, b); return c.u;
}
__device__ __forceinline__ float dot2(half2_t a, unsigned bw, float c) {
    PK b; b.u = bw;
    return __builtin_amdgcn_fdot2(a, b.h, c, false);
}

// ---- prep kernel ----------------------------------------------------------
// ws layout (uint32 words):
//   [0,32)    WqP[k][p]  = (Wq[2p][k], Wq[2p+1][k]) * INV2PI   (dot2 pairs)
//   [32,64)   WcP[kp][j] = (Wc[2kp][j], Wc[2kp+1][j])          (dot2 pairs)
//   [64,72)   qbias[k]   = (bq[k]+tha[k]) * INV2PI   (float bits)
//   [72,80)   cf[j]      = cos(theta_ffn[j])          (float bits)
//   [128,384) B1a frag:  uint4 per lane L: W1[j][n0] f16 pairs, q==0 else 0
//   [384,640) B1b frag:  same with n0+16
//   [640,896) B2  frag:  W2[8q+j][n0] f16 pairs, n0<8 else 0
// Frag layout: A/B[m|n = lane&15][k = (lane>>4)*8 + j], pairs (2p,2p+1) along k.
__global__ void pack_weights(const float* __restrict__ Wq,
                             const float* __restrict__ W1,
                             const float* __restrict__ W2,
                             const float* __restrict__ Wc,
                             const float* __restrict__ bq,
                             const float* __restrict__ tha,
                             const float* __restrict__ thf,
                             unsigned* __restrict__ ws)
{
    int idx = threadIdx.x;
    if (idx < 32) {
        int k = idx >> 2, p = idx & 3;
        ws[idx] = packh2(Wq[(2 * p) * 8 + k] * INV2PI, Wq[(2 * p + 1) * 8 + k] * INV2PI);
    } else if (idx < 64) {
        int i2 = idx - 32;
        int kp = i2 >> 3, j = i2 & 7;
        ws[idx] = packh2(Wc[(2 * kp) * 8 + j], Wc[(2 * kp + 1) * 8 + j]);
    } else if (idx < 72) {
        int k = idx - 64;
        ws[idx] = __float_as_uint((bq[k] + tha[k]) * INV2PI);
    } else if (idx < 80) {
        int j = idx - 72;
        ws[idx] = __float_as_uint(__builtin_amdgcn_cosf(thf[j] * INV2PI));
    } else if (idx >= 128 && idx < 320) {
        int t  = (idx - 128) & 63;          // lane id
        int tb = (idx - 128) >> 6;          // 0=B1a, 1=B1b, 2=B2
        int n0 = t & 15, q = t >> 4;
        uint4 w = make_uint4(0u, 0u, 0u, 0u);
        unsigned r[4] = {0u, 0u, 0u, 0u};
        if (tb == 0) {           // W1 [8][32], rows k<8 real (q==0)
            if (q == 0)
                for (int p = 0; p < 4; ++p)
                    r[p] = packh2(W1[(2 * p) * 32 + n0], W1[(2 * p + 1) * 32 + n0]);
        } else if (tb == 1) {
            if (q == 0)
                for (int p = 0; p < 4; ++p)
                    r[p] = packh2(W1[(2 * p) * 32 + n0 + 16], W1[(2 * p + 1) * 32 + n0 + 16]);
        } else {                 // W2 [32][8], cols n0<8 real, k = 8q+j
            if (n0 < 8)
                for (int p = 0; p < 4; ++p)
                    r[p] = packh2(W2[(8 * q + 2 * p) * 8 + n0], W2[(8 * q + 2 * p + 1) * 8 + n0]);
        }
        w.x = r[0]; w.y = r[1]; w.z = r[2]; w.w = r[3];
        reinterpret_cast<uint4*>(ws)[32 + tb * 64 + t] = w;
    }
}

// ---- main kernel ----------------------------------------------------------
__global__ __launch_bounds__(NTHREADS, 8)
void qtb_kernel(const float* __restrict__ x,
                const float* __restrict__ bc,
                const float* __restrict__ g1,  const float* __restrict__ be1,
                const float* __restrict__ b1,
                const float* __restrict__ b2,
                const float* __restrict__ g2,  const float* __restrict__ be2,
                const unsigned* __restrict__ wp,
                float* __restrict__ out)
{
    const int tid  = threadIdx.x;
    const int wave = tid >> 6;
    const int lane = tid & 63;
    const int col  = lane & 15;
    const int quad = lane >> 4;
    const int g    = blockIdx.x * NTHREADS + tid;   // token id

    // ---- x load first: start HBM latency before everything else ----
    const float4* px = reinterpret_cast<const float4*>(x) + (size_t)g * 2;
    float4 xa = px[0];
    float4 xb = px[1];

    const float* qb = reinterpret_cast<const float*>(wp + 64);
    const float* cf = reinterpret_cast<const float*>(wp + 72);

    // wave-private LDS slices (no __syncthreads needed; same-wave lgkmcnt ordering)
    __shared__ uint4    zbuf[4][64];        // zf f16x8 per token       (4 KB)
    __shared__ unsigned hbuf[4][16 * 20];   // h f16 pairs (j, j+16)    (5 KB)
    __shared__ float    fbuf[4][64 * 9];    // ffn transpose buffer     (9 KB)

    // ---- MFMA weight fragments + bias C-inits ----
    const uint4* fr = reinterpret_cast<const uint4*>(wp);
    U4H B1a, B1b, B2;
    B1a.u = fr[32 + lane];
    B1b.u = fr[96 + lane];
    B2.u  = fr[160 + lane];
    const float b1a_s = b1[col];
    const float b1b_s = b1[col + 16];
    const float b2_s  = (col < 8) ? b2[col & 7] : 0.f;

    float xv[8];
    half2_t xp[4];
    xv[0] = xa.x; xv[1] = xa.y; xv[2] = xa.z; xv[3] = xa.w;
    xv[4] = xb.x; xv[5] = xb.y; xv[6] = xb.z; xv[7] = xb.w;
    xp[0] = __builtin_amdgcn_cvt_pkrtz(xa.x, xa.y);
    xp[1] = __builtin_amdgcn_cvt_pkrtz(xa.z, xa.w);
    xp[2] = __builtin_amdgcn_cvt_pkrtz(xb.x, xb.y);
    xp[3] = __builtin_amdgcn_cvt_pkrtz(xb.z, xb.w);

    // ---- attention: q (revolutions) via dot2, cos, cumprods, z@Wc via dot2 ----
    float ca[8];
#pragma unroll
    for (int k = 0; k < 8; ++k) {
        float q = qb[k];
#pragma unroll
        for (int p = 0; p < 4; ++p) q = dot2(xp[p], wp[k * 4 + p], q);
        ca[k] = fast_cos_rev(q);
    }
    float attn[8];
#pragma unroll
    for (int j = 0; j < 8; ++j) attn[j] = bc[j];
    {
        float z[8];
        float cp  = ca[0];
        float cp1 = 1.0f;
#pragma unroll
        for (int k = 1; k < 8; ++k) {
            cp  *= ca[k];
            cp1 *= ca[k];
            z[k] = cp;
        }
        z[0] = cp1;
        half2_t zp[4];
#pragma unroll
        for (int p = 0; p < 4; ++p)
            zp[p] = __builtin_amdgcn_cvt_pkrtz(z[2 * p], z[2 * p + 1]);
#pragma unroll
        for (int p = 0; p < 4; ++p)
#pragma unroll
            for (int j = 0; j < 8; ++j)
                attn[j] = dot2(zp[p], wp[32 + p * 8 + j], attn[j]);
    }

    // ---- LN1 + zf = cf * cos(x1); keep x1 in xv ----
    {
        float y[8];
        float s = 0.f;
#pragma unroll
        for (int j = 0; j < 8; ++j) { y[j] = xv[j] + attn[j]; s += y[j]; }
        float m = s * 0.125f;
        float v = 0.f;
#pragma unroll
        for (int j = 0; j < 8; ++j) { float d = y[j] - m; v += d * d; }
        float r = fast_rsqrt(v * 0.125f + LN_EPS);
        float zf[8];
#pragma unroll
        for (int j = 0; j < 8; ++j) {
            float x1 = (y[j] - m) * r * g1[j] + be1[j];
            xv[j] = x1;
            zf[j] = cf[j] * fast_cos(x1);
        }
        U4H zpk;
#pragma unroll
        for (int p = 0; p < 4; ++p)
            zpk.h2[p] = __builtin_amdgcn_cvt_pkrtz(zf[2 * p], zf[2 * p + 1]);
        zbuf[wave][lane] = zpk.u;
    }

    // ---- FFN on MFMA: per 16-token group: GEMM1 (2 mfma) -> relu -> GEMM2 ----
    const unsigned psel = (quad < 2) ? 0x05040100u : 0x07060302u;  // lo/hi half pick
#pragma unroll
    for (int grp = 0; grp < 4; ++grp) {
        // A1: zf of token (grp*16 + col), broadcast across quads (k>=8 of B is 0)
        U4H A1; A1.u = zbuf[wave][grp * 16 + col];
        float4_t c1a = {b1a_s, b1a_s, b1a_s, b1a_s};
        float4_t c1b = {b1b_s, b1b_s, b1b_s, b1b_s};
        float4_t h0 = __builtin_amdgcn_mfma_f32_16x16x32_f16(A1.h, B1a.h, c1a, 0, 0, 0);
        float4_t h1 = __builtin_amdgcn_mfma_f32_16x16x32_f16(A1.h, B1b.h, c1b, 0, 0, 0);
        // relu + transpose via LDS: word[tok][c] = f16(h[tok][c], h[tok][c+16]), stride 20
#pragma unroll
        for (int r = 0; r < 4; ++r)
            hbuf[wave][(4 * quad + r) * 20 + col] =
                packh2(fmaxf(h0[r], 0.f), fmaxf(h1[r], 0.f));
        // A2: h[m=col][k=8*quad+j]; feats 8q+j live in words (quad&1)*8.., lo/hi by quad>>1
        int hb = col * 20 + (quad & 1) * 8;
        uint4 w0 = *reinterpret_cast<const uint4*>(&hbuf[wave][hb]);
        uint4 w1 = *reinterpret_cast<const uint4*>(&hbuf[wave][hb + 4]);
        U4H A2;
        A2.u.x = __builtin_amdgcn_perm(w0.y, w0.x, psel);
        A2.u.y = __builtin_amdgcn_perm(w0.w, w0.z, psel);
        A2.u.z = __builtin_amdgcn_perm(w1.y, w1.x, psel);
        A2.u.w = __builtin_amdgcn_perm(w1.w, w1.z, psel);
        float4_t c2 = {b2_s, b2_s, b2_s, b2_s};
        float4_t f = __builtin_amdgcn_mfma_f32_16x16x32_f16(A2.h, B2.h, c2, 0, 0, 0);
        // ffn out: D[tok=4*quad+r][j=col], only cols<8 valid; row stride 9
        if (col < 8) {
#pragma unroll
            for (int r = 0; r < 4; ++r)
                fbuf[wave][(grp * 16 + 4 * quad + r) * 9 + col] = f[r];
        }
    }

    // ---- LN2 + store ----
    {
        float y[8];
        float s = 0.f;
#pragma unroll
        for (int j = 0; j < 8; ++j) {
            y[j] = xv[j] + fbuf[wave][lane * 9 + j];
            s += y[j];
        }
        float m = s * 0.125f;
        float v = 0.f;
#pragma unroll
        for (int j = 0; j < 8; ++j) { float d = y[j] - m; v += d * d; }
        float r = fast_rsqrt(v * 0.125f + LN_EPS);
        float o[8];
#pragma unroll
        for (int j = 0; j < 8; ++j) o[j] = (y[j] - m) * r * g2[j] + be2[j];
        float4* q = reinterpret_cast<float4*>(out) + (size_t)g * 2;
        q[0] = make_float4(o[0], o[1], o[2], o[3]);
        q[1] = make_float4(o[4], o[5], o[6], o[7]);
    }
}

extern "C" void kernel_launch(void* const* d_in, const int* in_sizes, int n_in,
                              void* d_out, int out_size, void* d_ws, size_t ws_size,
                              hipStream_t stream) {
    (void)in_sizes; (void)n_in; (void)ws_size; (void)out_size;
    unsigned* wp = (unsigned*)d_ws;
    pack_weights<<<1, 320, 0, stream>>>(
        (const float*)d_in[1],   // Wq
        (const float*)d_in[9],   // W1
        (const float*)d_in[11],  // W2
        (const float*)d_in[4],   // Wc
        (const float*)d_in[2],   // bq
        (const float*)d_in[3],   // theta_attn
        (const float*)d_in[8],   // theta_ffn
        wp);
    qtb_kernel<<<NBLOCKS, NTHREADS, 0, stream>>>(
        (const float*)d_in[0],  // x
        (const float*)d_in[5],  // bc
        (const float*)d_in[6],  // g1
        (const float*)d_in[7],  // beta1
        (const float*)d_in[10], // b1
        (const float*)d_in[12], // b2
        (const float*)d_in[13], // g2
        (const float*)d_in[14], // beta2
        wp,
        (float*)d_out);
}